// Round 2
// baseline (1477.654 us; speedup 1.0000x reference)
//
#include <hip/hip_runtime.h>
#include <math.h>

#define D_MODEL 4096
#define NEXP    64
#define TOPK    8
#define NTOK    16384        // 4 * 4096
#define BLK_TOK 64
#define DC      128          // d per chunk
#define KSPLIT  2
#define KHALF   (D_MODEL / KSPLIT)   // 2048
#define NCHUNK_H (KHALF / DC)        // 16
#define EPW     4            // experts per wave
#define NWAVE   (NEXP / EPW) // 16
#define NTHR    (NWAVE * 64) // 1024

#define WT2_FLOATS (NEXP * D_MODEL)  // 262144 floats = 1 MB

typedef float v2f __attribute__((ext_vector_type(2)));

// WT2 layout: [g:16][d2:2048][j:4][p:2] where WT2[((g*2048+d2)*4+j)*2+p] = W[g*4+j][2*d2+p].
// Expert j's weights for consecutive d (2*d2, 2*d2+1) are an aligned pair -> SGPR pair
// feeding v_pk_fma_f32; 16 consecutive floats per 4-d group -> s_load_dwordx16.
__global__ void transpose_w_kernel(const float* __restrict__ W, float* __restrict__ WT2) {
    int o = blockIdx.x * 256 + threadIdx.x;    // 262144 total
    int p  = o & 1;
    int j  = (o >> 1) & 3;
    int d2 = (o >> 3) & 2047;
    int g  = o >> 14;
    WT2[o] = W[(size_t)(g * 4 + j) * D_MODEL + 2 * d2 + p];
}

// Grid: 512 blocks = 256 token-tiles x 2 K-halves. 1024 threads = 16 waves x 4 experts.
// Partial logits accumulate via atomicAdd into pre-zeroed out_p (order-invariant fp32 sum).
__global__ __launch_bounds__(NTHR, 8)
void router_kernel(const float* __restrict__ x, const float* __restrict__ WT2,
                   float* __restrict__ Pacc) {
    // x tile: 2 buffers x [d4:32][f4-slot:64], 64 KB exactly. XOR swizzle
    // slot = row ^ (d4&7): reads contiguous-permuted (conflict-free), writes spread
    // across all bank quads (was 16-way conflict unswizzled).
    __shared__ __align__(16) float lds[2 * 8192];

    const int tid  = threadIdx.x;
    const int lane = tid & 63;                                   // token within block
    const int g    = __builtin_amdgcn_readfirstlane(tid >> 6);   // wave id == expert group
    const int s    = blockIdx.x & 1;                             // K-half
    const int tok0 = (blockIdx.x >> 1) * BLK_TOK;
    const int kbase = s * KHALF;

    // staging mapping: 64 rows (tokens) x 16 threads/row, 2 float4 each = 128 d
    const int row  = tid >> 4;
    const int q    = tid & 15;
    const int rowX = row ^ (q & 7);          // swizzled slot (d4&7 == q&7 for both j)

    v2f acc2[EPW];
#pragma unroll
    for (int j = 0; j < EPW; ++j) acc2[j] = (v2f)0.f;

    float4 xr[2];
    const float* xbase = x + (size_t)(tok0 + row) * D_MODEL + kbase + q * 4;
    const float* wk    = WT2 + (g << 14);   // this wave's [2048][4][2] W slab (uniform)

    auto load_chunk = [&](int d0) {
#pragma unroll
        for (int j = 0; j < 2; ++j)
            xr[j] = *(const float4*)(xbase + d0 + j * 64);   // 16B/lane contiguous
    };
    auto store_chunk = [&](int buf) {
#pragma unroll
        for (int j = 0; j < 2; ++j)
            *(float4*)&lds[buf * 8192 + (q + j * 16) * 256 + rowX * 4] = xr[j];
    };
    auto compute_chunk = [&](int buf, int kk) {
        const float* wc = wk + (kbase / 2 + kk * (DC / 2)) * 8;  // uniform -> s_load
        const float* xb = &lds[buf * 8192];
#pragma unroll
        for (int d4 = 0; d4 < DC / 4; ++d4) {                // FULL unroll: static swizzle
            const int c = d4 & 7;
            const float4 xq = *(const float4*)(xb + d4 * 256 + ((lane ^ c) << 2));
            const float* wd = wc + d4 * 16;                  // 16 floats = 2 d2 x 4e x 2p
            const v2f xlo = {xq.x, xq.y};
            const v2f xhi = {xq.z, xq.w};
#pragma unroll
            for (int j = 0; j < EPW; ++j)
                acc2[j] = __builtin_elementwise_fma(xlo, *(const v2f*)(wd + j * 2), acc2[j]);
#pragma unroll
            for (int j = 0; j < EPW; ++j)
                acc2[j] = __builtin_elementwise_fma(xhi, *(const v2f*)(wd + 8 + j * 2), acc2[j]);
        }
    };

    // prologue
    load_chunk(0);
    store_chunk(0);
    __syncthreads();

    for (int kk = 0; kk < NCHUNK_H; ++kk) {
        if (kk + 1 < NCHUNK_H) load_chunk((kk + 1) * DC);    // global loads in flight
        compute_chunk(kk & 1, kk);
        if (kk + 1 < NCHUNK_H) store_chunk((kk + 1) & 1);    // other buffer: no read hazard
        __syncthreads();                                      // one barrier per chunk
    }

    // ---- epilogue: gather [64 tok][64 e] partials into LDS, atomic-accumulate ----
    float* lg = lds;                     // reuse buf0 region; last compute read buf1; synced
#pragma unroll
    for (int j = 0; j < EPW; ++j)
        lg[lane * 65 + g * EPW + j] = acc2[j].x + acc2[j].y;
    __syncthreads();

    {   // 1024 threads x 4 floats = full 64x64 tile
        const int t  = tid >> 4;
        const int e4 = (tid & 15) << 2;
        const float* src = &lg[t * 65 + e4];
        float* dst = &Pacc[(size_t)(tok0 + t) * NEXP + e4];
#pragma unroll
        for (int c = 0; c < 4; ++c) atomicAdd(dst + c, src[c]);
    }
}

// Softmax + top-9 + flag on the complete logits in out_p; overwrite out_p with probs.
__global__ __launch_bounds__(256)
void finalize_kernel(float* out_p, float* __restrict__ out_w, float* __restrict__ out_i,
                     int* __restrict__ cnt, int* __restrict__ list) {
    __shared__ float lg[BLK_TOK * 65];   // [64][65] logits/probs
    const int tid  = threadIdx.x;
    const int tok0 = blockIdx.x * BLK_TOK;

    for (int i = tid; i < BLK_TOK * 16; i += 256) {          // load tile into LDS
        const int t  = i >> 4;
        const int e4 = (i & 15) << 2;
        const float4 a = *(const float4*)&out_p[(size_t)(tok0 + t) * NEXP + e4];
        float* dst = &lg[t * 65 + e4];
        dst[0] = a.x; dst[1] = a.y; dst[2] = a.z; dst[3] = a.w;
    }
    __syncthreads();

    if (tid < 64) {                      // wave 0: one token per lane
        const int tok = tok0 + tid;
        float p[64];
        float m = -INFINITY;
#pragma unroll
        for (int e = 0; e < 64; ++e) {
            p[e] = lg[tid * 65 + e];
            m = fmaxf(m, p[e]);
        }
        float z = 0.f;
#pragma unroll
        for (int e = 0; e < 64; ++e) {
            p[e] = __expf(p[e] - m);
            z += p[e];
        }
        const float rz = 1.f / z;
#pragma unroll
        for (int e = 0; e < 64; ++e) {
            p[e] *= rz;
            lg[tid * 65 + e] = p[e];    // publish probs for cooperative store
        }

        // branch-free top-9 (strict > => lowest index on ties, matching lax.top_k)
        float tv[9]; int ti[9];
#pragma unroll
        for (int k = 0; k < 9; ++k) { tv[k] = -1.f; ti[k] = 0; }
        for (int e = 0; e < 64; ++e) {
            float v = p[e]; int idx = e;
#pragma unroll
            for (int k = 0; k < 9; ++k) {
                const bool gt = v > tv[k];
                const float nv = gt ? v : tv[k];
                const int   ni = gt ? idx : ti[k];
                const float ov = gt ? tv[k] : v;
                const int   oi = gt ? ti[k] : idx;
                tv[k] = nv; ti[k] = ni; v = ov; idx = oi;
            }
        }
        // ambiguity flag: adjacent relative gap below 2e-4 (fp32 err sigma ~3e-6 => 66x margin)
        int flag = 0;
#pragma unroll
        for (int k = 0; k < 8; ++k)
            if (tv[k] - tv[k + 1] <= tv[k] * 2e-4f + 1e-12f) flag = 1;
        if (flag) {
            int sidx = atomicAdd(cnt, 1);
            list[sidx] = tok;
        }

        float s8 = 0.f;
#pragma unroll
        for (int k = 0; k < 8; ++k) s8 += tv[k];
        const float denom = s8 + 1e-9f;
#pragma unroll
        for (int k = 0; k < 8; ++k) {
            out_w[tok * TOPK + k] = tv[k] / denom;
            out_i[tok * TOPK + k] = (float)ti[k];
        }
    }
    __syncthreads();

    // cooperative coalesced probs store: 64 tok x 16 float4
    for (int i = tid; i < BLK_TOK * 16; i += 256) {
        const int t  = i >> 4;
        const int e4 = (i & 15) << 2;
        const float* src = &lg[t * 65 + e4];
        *(float4*)&out_p[(size_t)(tok0 + t) * NEXP + e4] =
            make_float4(src[0], src[1], src[2], src[3]);
    }
}

// Repair: iterate compacted flagged-token list, recompute logits in fp64, rewrite w/i.
// 256 threads: expert = tid&63, d-quarter = tid>>6; LDS-reduce 4 partials.
__global__ __launch_bounds__(256)
void repair_kernel(const float* __restrict__ x, const float* __restrict__ W,
                   const int* __restrict__ cnt, const int* __restrict__ list,
                   float* __restrict__ out_w, float* __restrict__ out_i) {
    __shared__ float  xs[D_MODEL];   // 16 KB
    __shared__ double ls[4][NEXP];   // 2 KB
    const int tid = threadIdx.x;
    const int e   = tid & 63;
    const int w4  = tid >> 6;        // d-quarter 0..3
    const int n   = cnt[0];

    for (int i = blockIdx.x; i < n; i += gridDim.x) {
        const int tok = list[i];
        __syncthreads();             // protect xs reuse across iterations
        const float4* xsrc = (const float4*)(x + (size_t)tok * D_MODEL);
        for (int v = tid; v < D_MODEL / 4; v += 256)
            ((float4*)xs)[v] = xsrc[v];
        __syncthreads();

        const float* wrow = W + (size_t)e * D_MODEL + w4 * (D_MODEL / 4);
        const float* xrow = xs + w4 * (D_MODEL / 4);
        double s0 = 0., s1 = 0., s2 = 0., s3 = 0.;
        for (int d = 0; d < D_MODEL / 4; d += 4) {
            const float4 wv = *(const float4*)(wrow + d);
            const float4 xv = *(const float4*)(xrow + d);
            s0 += (double)xv.x * (double)wv.x;
            s1 += (double)xv.y * (double)wv.y;
            s2 += (double)xv.z * (double)wv.z;
            s3 += (double)xv.w * (double)wv.w;
        }
        ls[w4][e] = (s0 + s1) + (s2 + s3);
        __syncthreads();

        if (tid == 0) {
            double lsum[64];
            for (int k = 0; k < 64; ++k)
                lsum[k] = (ls[0][k] + ls[1][k]) + (ls[2][k] + ls[3][k]);
            double m = -1e300;
            for (int k = 0; k < 64; ++k) m = lsum[k] > m ? lsum[k] : m;
            double p[64], Z = 0.;
            for (int k = 0; k < 64; ++k) { p[k] = exp(lsum[k] - m); Z += p[k]; }
            for (int k = 0; k < 64; ++k) p[k] /= Z;

            double tv[8]; int ti[8];
            for (int k = 0; k < 8; ++k) { tv[k] = -1.; ti[k] = 0; }
            for (int k = 0; k < 64; ++k) {
                double v = p[k]; int idx = k;
                for (int u = 0; u < 8; ++u) {
                    const bool gt = v > tv[u];
                    const double nv = gt ? v : tv[u];
                    const int    ni = gt ? idx : ti[u];
                    const double ov = gt ? tv[u] : v;
                    const int    oi = gt ? ti[u] : idx;
                    tv[u] = nv; ti[u] = ni; v = ov; idx = oi;
                }
            }
            double s8 = 0.;
            for (int k = 0; k < 8; ++k) s8 += tv[k];
            const double denom = s8 + 1e-9;
            for (int k = 0; k < 8; ++k) {
                out_w[tok * TOPK + k] = (float)(tv[k] / denom);
                out_i[tok * TOPK + k] = (float)ti[k];
            }
        }
    }
}

extern "C" void kernel_launch(void* const* d_in, const int* in_sizes, int n_in,
                              void* d_out, int out_size, void* d_ws, size_t ws_size,
                              hipStream_t stream) {
    const float* x = (const float*)d_in[0];   // [4,4096,4096]
    const float* W = (const float*)d_in[1];   // [64,4096]

    // workspace layout identical to the proven round-0 kernel (~1.07 MB)
    float* WT2  = (float*)d_ws;                          // 1 MB
    int*   cnt  = (int*)((float*)d_ws + WT2_FLOATS);     // 1 int
    int*   list = cnt + 1;                               // up to 16384 ints

    float* out   = (float*)d_out;
    float* out_w = out;                       // [16384,8]
    float* out_i = out + NTOK * TOPK;         // [16384,8] (as float)
    float* out_p = out + 2 * NTOK * TOPK;     // [16384,64]; doubles as logit accumulator

    hipMemsetAsync(cnt, 0, sizeof(int), stream);
    hipMemsetAsync(out_p, 0, (size_t)NTOK * NEXP * sizeof(float), stream);
    transpose_w_kernel<<<WT2_FLOATS / 256, 256, 0, stream>>>(W, WT2);
    router_kernel<<<(NTOK / BLK_TOK) * KSPLIT, NTHR, 0, stream>>>(x, WT2, out_p);
    finalize_kernel<<<NTOK / BLK_TOK, 256, 0, stream>>>(out_p, out_w, out_i, cnt, list);
    repair_kernel<<<256, 256, 0, stream>>>(x, W, cnt, list, out_w, out_i);
}

// Round 3
// 550.782 us; speedup vs baseline: 2.6828x; 2.6828x over previous
//
#include <hip/hip_runtime.h>
#include <math.h>

#define D_MODEL 4096
#define NEXP    64
#define TOPK    8
#define NTOK    16384        // 4 * 4096
#define BLK_TOK 64
#define DC      64           // d per chunk
#define KSPLIT  4
#define KQ      (D_MODEL / KSPLIT)   // 1024 d per block
#define NCHUNK_Q (KQ / DC)           // 16
#define EPW     8            // experts per wave
#define NWAVE   (NEXP / EPW) // 8
#define NTHR    (NWAVE * 64) // 512

#define WT2_FLOATS (NEXP * D_MODEL)  // 262144 floats = 1 MB

typedef float v2f __attribute__((ext_vector_type(2)));

// WT2 layout: [g:8][d2:2048][j:8][p:2] where WT2[(((g*2048)+d2)*8+j)*2+p] = W[g*8+j][2*d2+p].
// Expert j's weights for consecutive d form an aligned pair -> SGPR pair feeding
// v_pk_fma_f32; 32 consecutive floats per 4-d group -> 2x s_load_dwordx16.
__global__ void transpose_w_kernel(const float* __restrict__ W, float* __restrict__ WT2) {
    int o = blockIdx.x * 256 + threadIdx.x;    // 262144 total
    int p  = o & 1;
    int j  = (o >> 1) & 7;
    int d2 = (o >> 4) & 2047;
    int g  = o >> 15;
    WT2[o] = W[(size_t)(g * 8 + j) * D_MODEL + 2 * d2 + p];
}

// Grid: 1024 blocks = 256 token-tiles x 4 K-quarters. 512 threads = 8 waves x 8 experts.
// 32 KB LDS -> 4 blocks/CU -> 32 waves/CU (100%). VGPR target <=64 (8 waves/SIMD).
// Partial logits accumulate via atomicAdd into pre-zeroed out_p (order-invariant fp32 sum).
__global__ __launch_bounds__(NTHR, 8)
void router_kernel(const float* __restrict__ x, const float* __restrict__ WT2,
                   float* __restrict__ Pacc) {
    // x tile: 2 buffers x [d4:16][f4-slot:64], 32 KB. XOR swizzle slot = row ^ q
    // (q == d4&7): reads contiguous-permuted (conflict-free b128), writes spread
    // across banks (proven: round-2 conflicts 1.47e7 -> 6.5e4 with this scheme).
    __shared__ __align__(16) float lds[2 * 4096];

    const int tid  = threadIdx.x;
    const int lane = tid & 63;                                   // token within block
    const int g    = __builtin_amdgcn_readfirstlane(tid >> 6);   // wave id == expert group
    const int s    = blockIdx.x & 3;                             // K-quarter
    const int tok0 = (blockIdx.x >> 2) * BLK_TOK;
    const int kbase = s * KQ;

    // staging mapping: 64 rows (tokens) x 8 threads/row, 2 float4 each = 64 d
    const int row  = tid >> 3;
    const int q    = tid & 7;

    v2f acc2[EPW];
#pragma unroll
    for (int j = 0; j < EPW; ++j) acc2[j] = (v2f)0.f;

    float4 xr[2];
    const float* xbase = x + (size_t)(tok0 + row) * D_MODEL + kbase + q * 4;
    const float* wk    = WT2 + (g << 15);   // this wave's [2048][8][2] W slab (uniform)

    auto load_chunk = [&](int d0) {
#pragma unroll
        for (int j = 0; j < 2; ++j)
            xr[j] = *(const float4*)(xbase + d0 + j * 32);    // 8 f4/row = 128B contiguous
    };
    auto store_chunk = [&](int buf) {
#pragma unroll
        for (int j = 0; j < 2; ++j)
            *(float4*)&lds[buf * 4096 + (q + j * 8) * 256 + ((row ^ q) << 2)] = xr[j];
    };
    auto compute_chunk = [&](int buf, int kk) {
        const float* wc = wk + kbase * 8 + kk * (DC * 8);     // uniform -> s_load
        const float* xb = &lds[buf * 4096];
#pragma unroll 2
        for (int d4 = 0; d4 < DC / 4; ++d4) {
            const float4 xq = *(const float4*)(xb + d4 * 256 + (((lane ^ (d4 & 7))) << 2));
            const float* wd = wc + d4 * 32;                   // 32 floats = 2 d2 x 8e x 2p
            const v2f xlo = {xq.x, xq.y};
            const v2f xhi = {xq.z, xq.w};
#pragma unroll
            for (int j = 0; j < EPW; ++j)
                acc2[j] = __builtin_elementwise_fma(xlo, *(const v2f*)(wd + j * 2), acc2[j]);
#pragma unroll
            for (int j = 0; j < EPW; ++j)
                acc2[j] = __builtin_elementwise_fma(xhi, *(const v2f*)(wd + 16 + j * 2), acc2[j]);
        }
    };

    // prologue
    load_chunk(0);
    store_chunk(0);
    __syncthreads();

    for (int kk = 0; kk < NCHUNK_Q; ++kk) {
        if (kk + 1 < NCHUNK_Q) load_chunk((kk + 1) * DC);    // global loads in flight
        compute_chunk(kk & 1, kk);
        if (kk + 1 < NCHUNK_Q) store_chunk((kk + 1) & 1);    // other buffer: no read hazard
        __syncthreads();                                      // one barrier per chunk
    }

    // ---- epilogue: gather [64 tok][64 e] partials into LDS, atomic-accumulate ----
    float* lg = lds;                     // reuse; last compute read other buf; synced below
#pragma unroll
    for (int j = 0; j < EPW; ++j)
        lg[lane * 65 + g * EPW + j] = acc2[j].x + acc2[j].y;
    __syncthreads();

    for (int i = tid; i < BLK_TOK * 16; i += NTHR) {   // 1024 float4-groups, 2 per thread
        const int t  = i >> 4;
        const int e4 = (i & 15) << 2;
        const float* src = &lg[t * 65 + e4];
        float* dst = &Pacc[(size_t)(tok0 + t) * NEXP + e4];
#pragma unroll
        for (int c = 0; c < 4; ++c) atomicAdd(dst + c, src[c]);
    }
}

// Softmax + top-9 + flag on the complete logits in out_p; overwrite out_p with probs.
__global__ __launch_bounds__(256)
void finalize_kernel(float* out_p, float* __restrict__ out_w, float* __restrict__ out_i,
                     int* __restrict__ cnt, int* __restrict__ list) {
    __shared__ float lg[BLK_TOK * 65];   // [64][65] logits/probs
    const int tid  = threadIdx.x;
    const int tok0 = blockIdx.x * BLK_TOK;

    for (int i = tid; i < BLK_TOK * 16; i += 256) {          // load tile into LDS
        const int t  = i >> 4;
        const int e4 = (i & 15) << 2;
        const float4 a = *(const float4*)&out_p[(size_t)(tok0 + t) * NEXP + e4];
        float* dst = &lg[t * 65 + e4];
        dst[0] = a.x; dst[1] = a.y; dst[2] = a.z; dst[3] = a.w;
    }
    __syncthreads();

    if (tid < 64) {                      // wave 0: one token per lane
        const int tok = tok0 + tid;
        float p[64];
        float m = -INFINITY;
#pragma unroll
        for (int e = 0; e < 64; ++e) {
            p[e] = lg[tid * 65 + e];
            m = fmaxf(m, p[e]);
        }
        float z = 0.f;
#pragma unroll
        for (int e = 0; e < 64; ++e) {
            p[e] = __expf(p[e] - m);
            z += p[e];
        }
        const float rz = 1.f / z;
#pragma unroll
        for (int e = 0; e < 64; ++e) {
            p[e] *= rz;
            lg[tid * 65 + e] = p[e];    // publish probs for cooperative store
        }

        // branch-free top-9 (strict > => lowest index on ties, matching lax.top_k)
        float tv[9]; int ti[9];
#pragma unroll
        for (int k = 0; k < 9; ++k) { tv[k] = -1.f; ti[k] = 0; }
        for (int e = 0; e < 64; ++e) {
            float v = p[e]; int idx = e;
#pragma unroll
            for (int k = 0; k < 9; ++k) {
                const bool gt = v > tv[k];
                const float nv = gt ? v : tv[k];
                const int   ni = gt ? idx : ti[k];
                const float ov = gt ? tv[k] : v;
                const int   oi = gt ? ti[k] : idx;
                tv[k] = nv; ti[k] = ni; v = ov; idx = oi;
            }
        }
        // ambiguity flag: adjacent relative gap below 2e-4 (fp32 err sigma ~3e-6 => 66x margin)
        int flag = 0;
#pragma unroll
        for (int k = 0; k < 8; ++k)
            if (tv[k] - tv[k + 1] <= tv[k] * 2e-4f + 1e-12f) flag = 1;
        if (flag) {
            int sidx = atomicAdd(cnt, 1);
            list[sidx] = tok;
        }

        float s8 = 0.f;
#pragma unroll
        for (int k = 0; k < 8; ++k) s8 += tv[k];
        const float denom = s8 + 1e-9f;
#pragma unroll
        for (int k = 0; k < 8; ++k) {
            out_w[tok * TOPK + k] = tv[k] / denom;
            out_i[tok * TOPK + k] = (float)ti[k];
        }
    }
    __syncthreads();

    // cooperative coalesced probs store: 64 tok x 16 float4
    for (int i = tid; i < BLK_TOK * 16; i += 256) {
        const int t  = i >> 4;
        const int e4 = (i & 15) << 2;
        const float* src = &lg[t * 65 + e4];
        *(float4*)&out_p[(size_t)(tok0 + t) * NEXP + e4] =
            make_float4(src[0], src[1], src[2], src[3]);
    }
}

// Repair: iterate compacted flagged-token list, recompute logits in fp64, rewrite w/i.
// 256 threads: expert = tid&63, d-quarter = tid>>6; LDS-reduce 4 partials.
__global__ __launch_bounds__(256)
void repair_kernel(const float* __restrict__ x, const float* __restrict__ W,
                   const int* __restrict__ cnt, const int* __restrict__ list,
                   float* __restrict__ out_w, float* __restrict__ out_i) {
    __shared__ float  xs[D_MODEL];   // 16 KB
    __shared__ double ls[4][NEXP];   // 2 KB
    const int tid = threadIdx.x;
    const int e   = tid & 63;
    const int w4  = tid >> 6;        // d-quarter 0..3
    const int n   = cnt[0];

    for (int i = blockIdx.x; i < n; i += gridDim.x) {
        const int tok = list[i];
        __syncthreads();             // protect xs reuse across iterations
        const float4* xsrc = (const float4*)(x + (size_t)tok * D_MODEL);
        for (int v = tid; v < D_MODEL / 4; v += 256)
            ((float4*)xs)[v] = xsrc[v];
        __syncthreads();

        const float* wrow = W + (size_t)e * D_MODEL + w4 * (D_MODEL / 4);
        const float* xrow = xs + w4 * (D_MODEL / 4);
        double s0 = 0., s1 = 0., s2 = 0., s3 = 0.;
        for (int d = 0; d < D_MODEL / 4; d += 4) {
            const float4 wv = *(const float4*)(wrow + d);
            const float4 xv = *(const float4*)(xrow + d);
            s0 += (double)xv.x * (double)wv.x;
            s1 += (double)xv.y * (double)wv.y;
            s2 += (double)xv.z * (double)wv.z;
            s3 += (double)xv.w * (double)wv.w;
        }
        ls[w4][e] = (s0 + s1) + (s2 + s3);
        __syncthreads();

        if (tid == 0) {
            double lsum[64];
            for (int k = 0; k < 64; ++k)
                lsum[k] = (ls[0][k] + ls[1][k]) + (ls[2][k] + ls[3][k]);
            double m = -1e300;
            for (int k = 0; k < 64; ++k) m = lsum[k] > m ? lsum[k] : m;
            double p[64], Z = 0.;
            for (int k = 0; k < 64; ++k) { p[k] = exp(lsum[k] - m); Z += p[k]; }
            for (int k = 0; k < 64; ++k) p[k] /= Z;

            double tv[8]; int ti[8];
            for (int k = 0; k < 8; ++k) { tv[k] = -1.; ti[k] = 0; }
            for (int k = 0; k < 64; ++k) {
                double v = p[k]; int idx = k;
                for (int u = 0; u < 8; ++u) {
                    const bool gt = v > tv[u];
                    const double nv = gt ? v : tv[u];
                    const int    ni = gt ? idx : ti[u];
                    const double ov = gt ? tv[u] : v;
                    const int    oi = gt ? ti[u] : idx;
                    tv[u] = nv; ti[u] = ni; v = ov; idx = oi;
                }
            }
            double s8 = 0.;
            for (int k = 0; k < 8; ++k) s8 += tv[k];
            const double denom = s8 + 1e-9;
            for (int k = 0; k < 8; ++k) {
                out_w[tok * TOPK + k] = (float)(tv[k] / denom);
                out_i[tok * TOPK + k] = (float)ti[k];
            }
        }
    }
}

extern "C" void kernel_launch(void* const* d_in, const int* in_sizes, int n_in,
                              void* d_out, int out_size, void* d_ws, size_t ws_size,
                              hipStream_t stream) {
    const float* x = (const float*)d_in[0];   // [4,4096,4096]
    const float* W = (const float*)d_in[1];   // [64,4096]

    // workspace layout identical to the proven round-0 kernel (~1.07 MB)
    float* WT2  = (float*)d_ws;                          // 1 MB
    int*   cnt  = (int*)((float*)d_ws + WT2_FLOATS);     // 1 int
    int*   list = cnt + 1;                               // up to 16384 ints

    float* out   = (float*)d_out;
    float* out_w = out;                       // [16384,8]
    float* out_i = out + NTOK * TOPK;         // [16384,8] (as float)
    float* out_p = out + 2 * NTOK * TOPK;     // [16384,64]; doubles as logit accumulator

    hipMemsetAsync(cnt, 0, sizeof(int), stream);
    hipMemsetAsync(out_p, 0, (size_t)NTOK * NEXP * sizeof(float), stream);
    transpose_w_kernel<<<WT2_FLOATS / 256, 256, 0, stream>>>(W, WT2);
    router_kernel<<<(NTOK / BLK_TOK) * KSPLIT, NTHR, 0, stream>>>(x, WT2, out_p);
    finalize_kernel<<<NTOK / BLK_TOK, 256, 0, stream>>>(out_p, out_w, out_i, cnt, list);
    repair_kernel<<<256, 256, 0, stream>>>(x, W, cnt, list, out_w, out_i);
}